// Round 7
// baseline (221.674 us; speedup 1.0000x reference)
//
#include <hip/hip_runtime.h>

typedef unsigned int u32;
typedef unsigned short u16;
typedef unsigned char u8;
typedef __attribute__((ext_vector_type(8))) __bf16 bf16x8;
typedef __attribute__((ext_vector_type(4))) float f32x4;
typedef __attribute__((ext_vector_type(4))) int i32x4;

#define NB 16384
#define NM 4096
#define ND 512
#define NOUT 128
#define L2E 1.44269504088896340736f

// ws layout: x_ws fp8 [rb(256)][kg64(64)][row(64)][8B]   (8 MB)
//            s_ws fp8 [mb(32)][kg64(64)][m(128)][8B]     (2 MB, pre-scaled by -2*gamma*log2e)
//            hw_ws bf16 [slab=(mb*16+kg)][o(128)][8]     (1 MB)
// x2g[16384] = gamma*log2e*||x||^2 ; s2g[4096] = gamma*log2e*||s||^2  (fp32-exact)

#define WAITLG(N) do { asm volatile("s_waitcnt vmcnt(" #N ") lgkmcnt(0)" ::: "memory"); \
                       __builtin_amdgcn_sched_barrier(0); } while (0)
#define LGKM(N) do { asm volatile("s_waitcnt lgkmcnt(" #N ")" ::: "memory"); \
                     __builtin_amdgcn_sched_barrier(0); } while (0)
#define SB0() __builtin_amdgcn_sched_barrier(0)

// ---------- helpers ----------
__device__ __forceinline__ u16 f2bf(float f) {
  u32 u = __float_as_uint(f);
  u += 0x7FFFu + ((u >> 16) & 1u);   // RNE
  return (u16)(u >> 16);
}

// manual fp32 -> e4m3fn (RNE, flush |v|<2^-6 to 0; |v| <= ~15 here so no sat needed)
__device__ __forceinline__ u8 f2fp8(float f) {
  u32 u = __float_as_uint(f);
  u32 s = (u >> 24) & 0x80u;
  u32 au = u & 0x7FFFFFFFu;
  if (au < 0x3C800000u) return (u8)s;          // below min normal -> 0
  au += 0x000FFFFFu + ((au >> 20) & 1u);       // RNE to 3 mantissa bits
  u32 e = (au >> 23) - 120u;                   // rebias 127 -> 7
  u32 m = (au >> 20) & 7u;
  return (u8)(s | (e << 3) | m);
}

__device__ __forceinline__ void stage16(const void* g, void* l) {
  __builtin_amdgcn_global_load_lds((__attribute__((address_space(1))) void*)g,
                                   (__attribute__((address_space(3))) void*)l,
                                   16, 0, 0);
}

// compiler-invisible b128 global load: no forced compiler vmcnt before the
// consumer; my counted waits cover it (HW vmcnt counts asm loads too)
__device__ __forceinline__ bf16x8 ldg_b128(const void* p) {
  i32x4 r;
  asm volatile("global_load_dwordx4 %0, %1, off" : "=&v"(r) : "v"(p) : "memory");
  return __builtin_bit_cast(bf16x8, r);
}

__device__ __forceinline__ uint4 pack8bf(float4 v0, float4 v1) {
  uint4 pk;
  pk.x = (u32)f2bf(v0.x) | ((u32)f2bf(v0.y) << 16);
  pk.y = (u32)f2bf(v0.z) | ((u32)f2bf(v0.w) << 16);
  pk.z = (u32)f2bf(v1.x) | ((u32)f2bf(v1.y) << 16);
  pk.w = (u32)f2bf(v1.z) | ((u32)f2bf(v1.w) << 16);
  return pk;
}

__device__ __forceinline__ uint2 pack8f8(float4 v0, float4 v1) {
  uint2 pk;
  pk.x = (u32)f2fp8(v0.x) | ((u32)f2fp8(v0.y) << 8) |
         ((u32)f2fp8(v0.z) << 16) | ((u32)f2fp8(v0.w) << 24);
  pk.y = (u32)f2fp8(v1.x) | ((u32)f2fp8(v1.y) << 8) |
         ((u32)f2fp8(v1.z) << 16) | ((u32)f2fp8(v1.w) << 24);
  return pk;
}

// ---------- merged prep ----------
// blocks [0,512): x tiles (fp8)   [512,640): support tiles (fp8, scaled)
// [640,672): head_w (bf16)        [672,736): zero d_out (64 blocks x 128 KB)
__global__ __launch_bounds__(256) void prep_all(const float* __restrict__ x,
                                                const float* __restrict__ s,
                                                const float* __restrict__ hw,
                                                const float* __restrict__ gamma_p,
                                                u8*  __restrict__ x_ws,
                                                u8*  __restrict__ s_ws,
                                                u16* __restrict__ hw_ws,
                                                float* __restrict__ x2g,
                                                float* __restrict__ s2g,
                                                float* __restrict__ out) {
  __shared__ uint2 t8[2048];       // 16 KB (x/s transpose, XOR-swizzled)
  __shared__ uint4 t16[2048];      // 32 KB (hw transpose)
  const int tid = threadIdx.x, bid = blockIdx.x;
  const int lane = tid & 63, w = tid >> 6;

  if (bid < 640) {
    const bool isx = bid < 512;
    const int blk = isx ? bid : (bid - 512);
    const float* src_m = isx ? x : s;
    u8*    dst_ws = isx ? x_ws : s_ws;
    float* sq_out = isx ? x2g : s2g;
    const float gl   = gamma_p[0] * L2E;
    const float cmul = isx ? 1.0f : (-2.0f * gl);
    const int big  = isx ? (blk >> 1) : (blk >> 2);
    const int roff = isx ? ((blk & 1) * 32) : ((blk & 3) * 32);
    const int rows = isx ? 64 : 128;

    #pragma unroll
    for (int p = 0; p < 8; ++p) {
      const int row = p * 4 + w;                      // local row 0..31
      const float* src = src_m + (size_t)(blk * 32 + row) * ND + lane * 8;
      float4 v0 = *(const float4*)src;
      float4 v1 = *(const float4*)(src + 4);
      float ss = v0.x*v0.x + v0.y*v0.y + v0.z*v0.z + v0.w*v0.w
               + v1.x*v1.x + v1.y*v1.y + v1.z*v1.z + v1.w*v1.w;
      #pragma unroll
      for (int off = 32; off > 0; off >>= 1) ss += __shfl_down(ss, off);
      if (lane == 0) sq_out[blk * 32 + row] = gl * ss;
      v0.x *= cmul; v0.y *= cmul; v0.z *= cmul; v0.w *= cmul;
      v1.x *= cmul; v1.y *= cmul; v1.z *= cmul; v1.w *= cmul;
      t8[lane * 32 + ((row + lane) & 31)] = pack8f8(v0, v1);   // kg = lane
    }
    __syncthreads();
    #pragma unroll
    for (int p = 0; p < 8; ++p) {
      const int kg = p * 8 + (tid >> 5);
      const int row = tid & 31;
      uint2 pk = t8[kg * 32 + ((row + kg) & 31)];
      *(uint2*)&dst_ws[(((size_t)(big * 64 + kg)) * rows + roff + row) * 8] = pk;
    }
  } else if (bid < 672) {
    // ---- head_w: m-chunk of 128 (bf16) ----
    const int blk = bid - 640;
    #pragma unroll
    for (int p = 0; p < 8; ++p) {
      const int o = p * 16 + (tid >> 4);
      const int kg = tid & 15;
      const float* src = hw + (size_t)o * NM + blk * 128 + kg * 8;
      float4 v0 = *(const float4*)src;
      float4 v1 = *(const float4*)(src + 4);
      t16[o * 16 + ((kg + o) & 15)] = pack8bf(v0, v1);
    }
    __syncthreads();
    #pragma unroll
    for (int it = 0; it < 8; ++it) {
      const int kg = it * 2 + (tid >> 7);
      const int o = tid & 127;
      uint4 pk = t16[o * 16 + ((kg + o) & 15)];
      *(uint4*)&hw_ws[(((size_t)(blk * 16 + kg)) * 128 + o) * 8] = pk;
    }
  } else {
    // ---- zero d_out: 64 blocks x 128 KB ----
    float4* o4 = (float4*)out;
    const float4 z = {0.f, 0.f, 0.f, 0.f};
    size_t base = (size_t)(bid - 672) * 8192 + tid;
    #pragma unroll 8
    for (int i = 0; i < 32; ++i) o4[base + (size_t)i * 256] = z;
  }
}

// ---------- main fused kernel ----------
// R7 = R5's zero-in-slot-wait discipline at K=128 slot size (R6's failure was the
// per-chunk LGKM0 rolling pipeline, not the slot size).
// 256 thr / 4 waves / 32x64 wave tile / (256,2). LDS 80KB dynamic: X 32K @0
// (resident), S ring 4x8K @32768, Ks 16K @65536. 32 slots T=mt*4+s, slot consumes
// tiles {2T,2T+1}; ALL fragments for slot T+1 (8 aF b64 + 16 bF b64) are read into
// parity pn DURING slot T's MFMA chunks; single end-of-slot WAITLG(0)+barrier.
// Lead-2 staging: tiles {2T+4,2T+5} (buf (2T)&3 pair, freed by end-of-(T-1)
// barrier) issued at TOP of slot T, drained by end-of-T WAITLG(0) (~free: full
// slot of cover). b2(T+1) asm-issued at top of T (parity (s+1)&1), consumed at
// T+1. a2 (Ks(mt-1), slab s) read mid-slot, guaranteed by counted lgkmcnt(4)
// (a2 + 4 younger bF kc3 reads; DS completes in-order). gemm2 = 8 bf16 MFMA
// every slot (mt>0). Hazards: ring WAR via end-of-slot barrier; prologue needs a
// 2nd barrier after slot-0 frag reads (slot-0 stage overwrites bufs 0,1).
__global__ __launch_bounds__(256, 2)
void rbf_fused(const u8* __restrict__ x_ws, const u8* __restrict__ s_ws,
               const u16* __restrict__ hw_ws, const float* __restrict__ x2g,
               const float* __restrict__ s2g, const float* __restrict__ head_b,
               const float* __restrict__ scale_p, const float* __restrict__ shift_p,
               float* __restrict__ out)
{
  extern __shared__ __align__(16) char smem[];   // 80 KB dynamic

  const int tid  = threadIdx.x;
  const int w    = tid >> 6;
  const int lane = tid & 63;
  const int quad = lane >> 4;
  const int l16  = lane & 15;
  const int wr   = w & 1;    // row half (32 rows)
  const int wc   = w >> 1;   // m / out-col half (64)
  const int xcd  = blockIdx.x & 7;
  const int rb   = (blockIdx.x >> 3) * 2 + (xcd & 1);
  const int half = xcd >> 1;
  const int b0   = rb * 64;

  const float vscale = scale_p[0];
  const float vshift = shift_p[0];

  const u8* xsrc = x_ws + (size_t)rb * 32768;
  const u8* ssrc = s_ws + (size_t)(half * 8) * 65536;

  auto stage_tile = [&](int j) {         // tile j (K=64 chunk), 8 KB -> buf j&3
    const u8* sp = ssrc + (size_t)(j >> 3) * 65536 + (j & 7) * 8192;
    char* dp = smem + 32768 + (j & 3) * 8192;
    stage16(sp + tid * 16, dp + tid * 16);
    stage16(sp + 4096 + tid * 16, dp + 4096 + tid * 16);
  };

  // ---- prologue: x2v(2 ev), X->LDS(8 ev), tiles 0..3 (8 ev) ----
  f32x4 x2v[2];
  #pragma unroll
  for (int r = 0; r < 2; ++r)
    x2v[r] = *(const f32x4*)&x2g[b0 + wr * 32 + r * 16 + quad * 4];
  SB0();
  #pragma unroll
  for (int i = 0; i < 8; ++i)
    stage16(xsrc + i * 4096 + tid * 16, smem + i * 4096 + tid * 16);
  SB0();
  #pragma unroll
  for (int j = 0; j < 4; ++j) stage_tile(j);
  asm volatile("s_waitcnt vmcnt(4)" ::: "memory");   // drain x2v,X,tiles0,1; leave 2,3
  SB0();
  __builtin_amdgcn_s_barrier();
  SB0();

  // fragment double-buffers
  long long aF[2][4][2];     // [parity][kc][r]
  long long bF[2][4][4];     // [parity][kc][c]
  bf16x8 b2[2][4];           // gemm2 B: issued at T for T+1, parity (s+1)&1
  bf16x8 a2[2];

  // ---- frag reads for slot 0 -> parity 0 ----
  #pragma unroll
  for (int i = 0; i < 4; ++i)
    #pragma unroll
    for (int r = 0; r < 2; ++r)
      aF[0][i][r] = *(const long long*)(smem + ((i * 4 + quad) * 64 + wr * 32 + r * 16 + l16) * 8);
  #pragma unroll
  for (int i = 0; i < 4; ++i)       // kc i: tile i>>1 (bufs 0,1), kcL i&1
    #pragma unroll
    for (int c = 0; c < 4; ++c)
      bF[0][i][c] = *(const long long*)(smem + 32768 + (i >> 1) * 8192 +
                     (((i & 1) * 4 + quad) * 128 + wc * 64 + c * 16 + l16) * 8);
  LGKM(0);
  __builtin_amdgcn_s_barrier();   // all waves done reading bufs 0,1 before slot-0 stage
  SB0();

  const f32x4 zf = {0.f, 0.f, 0.f, 0.f};
  f32x4 acc_xs[2][4];
  f32x4 acc_out[2][4];
  #pragma unroll
  for (int r = 0; r < 2; ++r)
    #pragma unroll
    for (int c = 0; c < 4; ++c) { acc_xs[r][c] = zf; acc_out[r][c] = zf; }

  #pragma unroll 1
  for (int mt = 0; mt < 8; ++mt) {
    const int mtg = half * 8 + mt;
    float s2v[4];

    #pragma unroll
    for (int s = 0; s < 4; ++s) {
      const int p  = s & 1;
      const int pn = p ^ 1;
      const int sN = (s + 1) & 3;                  // next slot's X chunk
      const bool doRd = !(mt == 7 && s == 3);
      const bool doSt = (mt * 4 + s) <= 29;

      // ---- top of slot: s2v / stage(T+2) / b2(T+1) ----
      if (s == 0) {
        #pragma unroll
        for (int c = 0; c < 4; ++c)
          s2v[c] = s2g[mtg * 128 + wc * 64 + c * 16 + l16];
        SB0();
      }
      if (doSt) {
        const int j = (mt * 4 + s) * 2 + 4;
        stage_tile(j);
        stage_tile(j + 1);
      }
      SB0();
      if ((s < 3 && mt >= 1) || (s == 3 && mt <= 6)) {
        const int um = (s < 3) ? mt : (mt + 1);
        const size_t sb = (size_t)((half * 8 + um - 1) * 16 + sN * 4 + quad);
        #pragma unroll
        for (int c = 0; c < 4; ++c)
          b2[sN & 1][c] = ldg_b128(hw_ws + (sb * 128 + wc * 64 + c * 16 + l16) * 8);
      }
      SB0();

      const int jn = (mt * 4 + s) * 2 + 2;        // first tile of slot T+1

      // ---- chunk 0: MFMA kc0 | rdA kc0,kc1 + rdB kc0 ----
      __builtin_amdgcn_s_setprio(1);
      #pragma unroll
      for (int r = 0; r < 2; ++r)
        #pragma unroll
        for (int c = 0; c < 4; ++c)
          acc_xs[r][c] = __builtin_amdgcn_mfma_f32_16x16x32_fp8_fp8(
              aF[p][0][r], bF[p][0][c], acc_xs[r][c], 0, 0, 0);
      __builtin_amdgcn_s_setprio(0);
      SB0();
      if (doRd) {
        #pragma unroll
        for (int i = 0; i < 2; ++i)
          #pragma unroll
          for (int r = 0; r < 2; ++r)
            aF[pn][i][r] = *(const long long*)(smem +
                (((sN * 4 + i) * 4 + quad) * 64 + wr * 32 + r * 16 + l16) * 8);
        #pragma unroll
        for (int c = 0; c < 4; ++c)
          bF[pn][0][c] = *(const long long*)(smem + 32768 + (jn & 3) * 8192 +
              ((0 * 4 + quad) * 128 + wc * 64 + c * 16 + l16) * 8);
      }
      SB0();

      // ---- chunk 1: MFMA kc1 | rdB kc1 + rdA kc2,kc3 ----
      __builtin_amdgcn_s_setprio(1);
      #pragma unroll
      for (int r = 0; r < 2; ++r)
        #pragma unroll
        for (int c = 0; c < 4; ++c)
          acc_xs[r][c] = __builtin_amdgcn_mfma_f32_16x16x32_fp8_fp8(
              aF[p][1][r], bF[p][1][c], acc_xs[r][c], 0, 0, 0);
      __builtin_amdgcn_s_setprio(0);
      SB0();
      if (doRd) {
        #pragma unroll
        for (int c = 0; c < 4; ++c)
          bF[pn][1][c] = *(const long long*)(smem + 32768 + (jn & 3) * 8192 +
              ((1 * 4 + quad) * 128 + wc * 64 + c * 16 + l16) * 8);
        #pragma unroll
        for (int i = 2; i < 4; ++i)
          #pragma unroll
          for (int r = 0; r < 2; ++r)
            aF[pn][i][r] = *(const long long*)(smem +
                (((sN * 4 + i) * 4 + quad) * 64 + wr * 32 + r * 16 + l16) * 8);
      }
      SB0();

      // ---- chunk 2: MFMA kc2 | rdB kc2 ----
      __builtin_amdgcn_s_setprio(1);
      #pragma unroll
      for (int r = 0; r < 2; ++r)
        #pragma unroll
        for (int c = 0; c < 4; ++c)
          acc_xs[r][c] = __builtin_amdgcn_mfma_f32_16x16x32_fp8_fp8(
              aF[p][2][r], bF[p][2][c], acc_xs[r][c], 0, 0, 0);
      __builtin_amdgcn_s_setprio(0);
      SB0();
      if (doRd) {
        #pragma unroll
        for (int c = 0; c < 4; ++c)
          bF[pn][2][c] = *(const long long*)(smem + 32768 + ((jn + 1) & 3) * 8192 +
              ((0 * 4 + quad) * 128 + wc * 64 + c * 16 + l16) * 8);
      }
      SB0();

      // ---- chunk 3: MFMA kc3 | a2 + rdB kc3 ----
      __builtin_amdgcn_s_setprio(1);
      #pragma unroll
      for (int r = 0; r < 2; ++r)
        #pragma unroll
        for (int c = 0; c < 4; ++c)
          acc_xs[r][c] = __builtin_amdgcn_mfma_f32_16x16x32_fp8_fp8(
              aF[p][3][r], bF[p][3][c], acc_xs[r][c], 0, 0, 0);
      __builtin_amdgcn_s_setprio(0);
      SB0();
      if (mt > 0) {
        const int kg = s * 4 + quad;
        #pragma unroll
        for (int r = 0; r < 2; ++r)
          a2[r] = *(const bf16x8*)(smem + 65536 + (kg * 64 + wr * 32 + r * 16 + l16) * 16);
      }
      if (doRd) {
        #pragma unroll
        for (int c = 0; c < 4; ++c)
          bF[pn][3][c] = *(const long long*)(smem + 32768 + ((jn + 1) & 3) * 8192 +
              ((1 * 4 + quad) * 128 + wc * 64 + c * 16 + l16) * 8);
      }
      SB0();

      // ---- gemm2: counted lgkm for a2, then 8 bf16 MFMA (regs only) ----
      if (mt > 0) {
        if (doRd) { LGKM(4); } else { LGKM(0); }
        __builtin_amdgcn_s_setprio(1);
        #pragma unroll
        for (int r = 0; r < 2; ++r)
          #pragma unroll
          for (int c = 0; c < 4; ++c)
            acc_out[r][c] = __builtin_amdgcn_mfma_f32_16x16x32_bf16(
                a2[r], b2[p][c], acc_out[r][c], 0, 0, 0);
        __builtin_amdgcn_s_setprio(0);
      }

      // ---- end of slot: drain everything issued this slot; barrier ----
      WAITLG(0);
      __builtin_amdgcn_s_barrier();
      SB0();
    }

    // ---- epilogue: t = acc + x2g + s2g ; k = min(exp2(-t),1) -> bf16 Ks ----
    {
      #pragma unroll
      for (int r = 0; r < 2; ++r)
        #pragma unroll
        for (int c = 0; c < 4; ++c) {
          const int cl = wc * 64 + c * 16 + l16;     // m-col 0..127
          char* kbase = smem + 65536 + (cl >> 3) * 1024 + (cl & 7) * 2;
          #pragma unroll
          for (int i = 0; i < 4; ++i) {
            const int row = wr * 32 + r * 16 + quad * 4 + i;
            const float t = acc_xs[r][c][i] + x2v[r][i] + s2v[c];
            float kv = __builtin_amdgcn_exp2f(-t);
            kv = fminf(kv, 1.0f);
            *(u16*)(kbase + row * 16) = (u16)(__float_as_uint(kv) >> 16);
            acc_xs[r][c][i] = 0.0f;
          }
        }
    }
    // lgkm-only barrier: Ks writes ordered before next mt's a2 reads; in-flight
    // stages/b2 (issued during slot (mt,3)) stay in flight
    LGKM(0);
    __builtin_amdgcn_s_barrier();
    SB0();
  }

  // ---- drained GEMM2 for the last mtile (Ks(7)) ----
  #pragma unroll
  for (int ks = 0; ks < 4; ++ks) {
    const int kg = ks * 4 + quad;
    const size_t sb = (size_t)((half * 8 + 7) * 16 + kg);
    bf16x8 bb[4], aa[2];
    #pragma unroll
    for (int c = 0; c < 4; ++c)
      bb[c] = *(const bf16x8*)(hw_ws + (sb * 128 + wc * 64 + c * 16 + l16) * 8);
    #pragma unroll
    for (int r = 0; r < 2; ++r)
      aa[r] = *(const bf16x8*)(smem + 65536 + (kg * 64 + wr * 32 + r * 16 + l16) * 16);
    #pragma unroll
    for (int r = 0; r < 2; ++r)
      #pragma unroll
      for (int c = 0; c < 4; ++c)
        acc_out[r][c] = __builtin_amdgcn_mfma_f32_16x16x32_bf16(aa[r], bb[c], acc_out[r][c], 0, 0, 0);
  }

  // ---- final: atomic-accumulate scale*acc (+ bias/shift once, by half==0 blocks) ----
  float addv[4];
  #pragma unroll
  for (int c = 0; c < 4; ++c) {
    const int col = wc * 64 + c * 16 + l16;
    addv[c] = (half == 0) ? (vscale * head_b[col] + vshift) : 0.0f;
  }
  #pragma unroll
  for (int r = 0; r < 2; ++r)
    #pragma unroll
    for (int c = 0; c < 4; ++c) {
      const int col = wc * 64 + c * 16 + l16;
      #pragma unroll
      for (int i = 0; i < 4; ++i) {
        const int row = b0 + wr * 32 + r * 16 + quad * 4 + i;
        atomicAdd(&out[(size_t)row * NOUT + col], vscale * acc_out[r][c][i] + addv[c]);
      }
    }
}

// ---------- launch ----------
extern "C" void kernel_launch(void* const* d_in, const int* in_sizes, int n_in,
                              void* d_out, int out_size, void* d_ws, size_t ws_size,
                              hipStream_t stream) {
  const float* x       = (const float*)d_in[0];
  const float* support = (const float*)d_in[1];
  const float* gamma   = (const float*)d_in[2];
  const float* head_w  = (const float*)d_in[3];
  const float* head_b  = (const float*)d_in[4];
  const float* scale   = (const float*)d_in[5];
  const float* shift   = (const float*)d_in[6];
  float* out = (float*)d_out;

  char* w = (char*)d_ws;
  u8*    x_ws  = (u8*)(w);                        //  8,388,608 B
  u8*    s_ws  = (u8*)(w + 8388608);              //  2,097,152 B
  u16*   hw_ws = (u16*)(w + 10485760);            //  1,048,576 B
  float* x2g   = (float*)(w + 11534336);          //     65,536 B
  float* s2g   = (float*)(w + 11599872);          //     16,384 B

  static bool lds_init = false;
  if (!lds_init) {
    hipFuncSetAttribute(reinterpret_cast<const void*>(rbf_fused),
                        hipFuncAttributeMaxDynamicSharedMemorySize, 81920);
    lds_init = true;
  }

  prep_all<<<736, 256, 0, stream>>>(x, support, head_w, gamma,
                                    x_ws, s_ws, hw_ws, x2g, s2g, out);
  rbf_fused<<<1024, 256, 81920, stream>>>(x_ws, s_ws, hw_ws, x2g, s2g,
                                          head_b, scale, shift, out);
}

// Round 8
// 182.320 us; speedup vs baseline: 1.2159x; 1.2159x over previous
//
#include <hip/hip_runtime.h>

typedef unsigned int u32;
typedef unsigned short u16;
typedef unsigned char u8;
typedef __attribute__((ext_vector_type(8))) __bf16 bf16x8;
typedef __attribute__((ext_vector_type(4))) float f32x4;
typedef __attribute__((ext_vector_type(4))) int i32x4;

#define NB 16384
#define NM 4096
#define ND 512
#define NOUT 128
#define L2E 1.44269504088896340736f

// ws layout: x_ws fp8 [rb(256)][kg64(64)][row(64)][8B]   (8 MB)
//            s_ws fp8 [mb(32)][kg64(64)][m(128)][8B]     (2 MB, pre-scaled by -2*gamma*log2e)
//            hw_ws bf16 [slab=(mb*16+kg)][o(128)][8]     (1 MB)
// x2g[16384] = gamma*log2e*||x||^2 ; s2g[4096] = gamma*log2e*||s||^2  (fp32-exact)

#define WAITLG(N) do { asm volatile("s_waitcnt vmcnt(" #N ") lgkmcnt(0)" ::: "memory"); \
                       __builtin_amdgcn_sched_barrier(0); } while (0)
#define LGKM(N) do { asm volatile("s_waitcnt lgkmcnt(" #N ")" ::: "memory"); \
                     __builtin_amdgcn_sched_barrier(0); } while (0)
#define SB0() __builtin_amdgcn_sched_barrier(0)

// ---------- helpers ----------
__device__ __forceinline__ u16 f2bf(float f) {
  u32 u = __float_as_uint(f);
  u += 0x7FFFu + ((u >> 16) & 1u);   // RNE
  return (u16)(u >> 16);
}

// manual fp32 -> e4m3fn (RNE, flush |v|<2^-6 to 0; |v| <= ~15 here so no sat needed)
__device__ __forceinline__ u8 f2fp8(float f) {
  u32 u = __float_as_uint(f);
  u32 s = (u >> 24) & 0x80u;
  u32 au = u & 0x7FFFFFFFu;
  if (au < 0x3C800000u) return (u8)s;          // below min normal -> 0
  au += 0x000FFFFFu + ((au >> 20) & 1u);       // RNE to 3 mantissa bits
  u32 e = (au >> 23) - 120u;                   // rebias 127 -> 7
  u32 m = (au >> 20) & 7u;
  return (u8)(s | (e << 3) | m);
}

__device__ __forceinline__ void stage16(const void* g, void* l) {
  __builtin_amdgcn_global_load_lds((__attribute__((address_space(1))) void*)g,
                                   (__attribute__((address_space(3))) void*)l,
                                   16, 0, 0);
}

// compiler-invisible b128 global load: no forced compiler vmcnt before the
// consumer; my counted waits cover it (HW vmcnt counts asm loads too)
__device__ __forceinline__ bf16x8 ldg_b128(const void* p) {
  i32x4 r;
  asm volatile("global_load_dwordx4 %0, %1, off" : "=&v"(r) : "v"(p) : "memory");
  return __builtin_bit_cast(bf16x8, r);
}

__device__ __forceinline__ uint4 pack8bf(float4 v0, float4 v1) {
  uint4 pk;
  pk.x = (u32)f2bf(v0.x) | ((u32)f2bf(v0.y) << 16);
  pk.y = (u32)f2bf(v0.z) | ((u32)f2bf(v0.w) << 16);
  pk.z = (u32)f2bf(v1.x) | ((u32)f2bf(v1.y) << 16);
  pk.w = (u32)f2bf(v1.z) | ((u32)f2bf(v1.w) << 16);
  return pk;
}

__device__ __forceinline__ uint2 pack8f8(float4 v0, float4 v1) {
  uint2 pk;
  pk.x = (u32)f2fp8(v0.x) | ((u32)f2fp8(v0.y) << 8) |
         ((u32)f2fp8(v0.z) << 16) | ((u32)f2fp8(v0.w) << 24);
  pk.y = (u32)f2fp8(v1.x) | ((u32)f2fp8(v1.y) << 8) |
         ((u32)f2fp8(v1.z) << 16) | ((u32)f2fp8(v1.w) << 24);
  return pk;
}

// ---------- merged prep ----------
// blocks [0,512): x tiles (fp8)   [512,640): support tiles (fp8, scaled)
// [640,672): head_w (bf16)        [672,736): zero d_out (64 blocks x 128 KB)
__global__ __launch_bounds__(256) void prep_all(const float* __restrict__ x,
                                                const float* __restrict__ s,
                                                const float* __restrict__ hw,
                                                const float* __restrict__ gamma_p,
                                                u8*  __restrict__ x_ws,
                                                u8*  __restrict__ s_ws,
                                                u16* __restrict__ hw_ws,
                                                float* __restrict__ x2g,
                                                float* __restrict__ s2g,
                                                float* __restrict__ out) {
  __shared__ uint2 t8[2048];       // 16 KB (x/s transpose, XOR-swizzled)
  __shared__ uint4 t16[2048];      // 32 KB (hw transpose)
  const int tid = threadIdx.x, bid = blockIdx.x;
  const int lane = tid & 63, w = tid >> 6;

  if (bid < 640) {
    const bool isx = bid < 512;
    const int blk = isx ? bid : (bid - 512);
    const float* src_m = isx ? x : s;
    u8*    dst_ws = isx ? x_ws : s_ws;
    float* sq_out = isx ? x2g : s2g;
    const float gl   = gamma_p[0] * L2E;
    const float cmul = isx ? 1.0f : (-2.0f * gl);
    const int big  = isx ? (blk >> 1) : (blk >> 2);
    const int roff = isx ? ((blk & 1) * 32) : ((blk & 3) * 32);
    const int rows = isx ? 64 : 128;

    #pragma unroll
    for (int p = 0; p < 8; ++p) {
      const int row = p * 4 + w;                      // local row 0..31
      const float* src = src_m + (size_t)(blk * 32 + row) * ND + lane * 8;
      float4 v0 = *(const float4*)src;
      float4 v1 = *(const float4*)(src + 4);
      float ss = v0.x*v0.x + v0.y*v0.y + v0.z*v0.z + v0.w*v0.w
               + v1.x*v1.x + v1.y*v1.y + v1.z*v1.z + v1.w*v1.w;
      #pragma unroll
      for (int off = 32; off > 0; off >>= 1) ss += __shfl_down(ss, off);
      if (lane == 0) sq_out[blk * 32 + row] = gl * ss;
      v0.x *= cmul; v0.y *= cmul; v0.z *= cmul; v0.w *= cmul;
      v1.x *= cmul; v1.y *= cmul; v1.z *= cmul; v1.w *= cmul;
      t8[lane * 32 + ((row + lane) & 31)] = pack8f8(v0, v1);   // kg = lane
    }
    __syncthreads();
    #pragma unroll
    for (int p = 0; p < 8; ++p) {
      const int kg = p * 8 + (tid >> 5);
      const int row = tid & 31;
      uint2 pk = t8[kg * 32 + ((row + kg) & 31)];
      *(uint2*)&dst_ws[(((size_t)(big * 64 + kg)) * rows + roff + row) * 8] = pk;
    }
  } else if (bid < 672) {
    // ---- head_w: m-chunk of 128 (bf16) ----
    const int blk = bid - 640;
    #pragma unroll
    for (int p = 0; p < 8; ++p) {
      const int o = p * 16 + (tid >> 4);
      const int kg = tid & 15;
      const float* src = hw + (size_t)o * NM + blk * 128 + kg * 8;
      float4 v0 = *(const float4*)src;
      float4 v1 = *(const float4*)(src + 4);
      t16[o * 16 + ((kg + o) & 15)] = pack8bf(v0, v1);
    }
    __syncthreads();
    #pragma unroll
    for (int it = 0; it < 8; ++it) {
      const int kg = it * 2 + (tid >> 7);
      const int o = tid & 127;
      uint4 pk = t16[o * 16 + ((kg + o) & 15)];
      *(uint4*)&hw_ws[(((size_t)(blk * 16 + kg)) * 128 + o) * 8] = pk;
    }
  } else {
    // ---- zero d_out: 64 blocks x 128 KB ----
    float4* o4 = (float4*)out;
    const float4 z = {0.f, 0.f, 0.f, 0.f};
    size_t base = (size_t)(bid - 672) * 8192 + tid;
    #pragma unroll 8
    for (int i = 0; i < 32; ++i) o4[base + (size_t)i * 256] = z;
  }
}

// ---------- main fused kernel ----------
// R8 = R5 (93us anchor: 256thr/4waves/32x64 tile, X 32K @0, S ring 4x8K @32768,
// Ks 16K @65536, register frag pipeline aF/bF parity, VGPR 120) with HALF the
// sync points: 2-slot intervals {even grp, odd grp}.
//   even slot: [s2v@g0][stage g+3 AND g+4][b2 for g+2][MFMA p=0 w/ embedded reads
//              for g+1 -> parity 1][gemm2][LGKM(0)]            <- no barrier!
//   odd slot:  [MFMA p=1 w/ embedded reads for g+2 -> parity 0][WAITLG(0)]
//              [s_barrier]
// Ring hazard (lead 3/4, both stages at even-slot top): write-bufs {g+3,g}&3 are
// disjoint from the interval's read-bufs {g+1,g+2}&3; all cross-wave reads of the
// write-bufs drained at the previous barrier's lgkm0. Interval-end vmcnt(0) drain
// is benign: stages issued ~2600cyc earlier >> ~900cyc HBM latency at 212GB/s
// load. b2 issued at even slot for consumer g+2 (crosses one barrier ✓); mt0's
// dummy b2 loads deleted (wait counts no longer need uniformity). R7's lesson:
// do NOT exceed ~130 VGPR demand (allocator pins at 128 and spills) — this keeps
// R5's exact register arrays.
__global__ __launch_bounds__(256, 2)
void rbf_fused(const u8* __restrict__ x_ws, const u8* __restrict__ s_ws,
               const u16* __restrict__ hw_ws, const float* __restrict__ x2g,
               const float* __restrict__ s2g, const float* __restrict__ head_b,
               const float* __restrict__ scale_p, const float* __restrict__ shift_p,
               float* __restrict__ out)
{
  extern __shared__ __align__(16) char smem[];   // 80 KB dynamic

  const int tid  = threadIdx.x;
  const int w    = tid >> 6;
  const int lane = tid & 63;
  const int quad = lane >> 4;
  const int l16  = lane & 15;
  const int wr   = w & 1;    // row half (32 rows)
  const int wc   = w >> 1;   // m / out-col half (64)
  const int xcd  = blockIdx.x & 7;
  const int rb   = (blockIdx.x >> 3) * 2 + (xcd & 1);
  const int half = xcd >> 1;
  const int b0   = rb * 64;

  const float vscale = scale_p[0];
  const float vshift = shift_p[0];

  const u8* xsrc = x_ws + (size_t)rb * 32768;
  const u8* ssrc = s_ws + (size_t)(half * 8) * 65536;

  auto stage_grp = [&](int mt_s, int grp_s) {
    const u8* sp = ssrc + (size_t)mt_s * 65536 + grp_s * 8192;
    char* dp = smem + 32768 + (grp_s & 3) * 8192;
    stage16(sp + tid * 16, dp + tid * 16);
    stage16(sp + 4096 + tid * 16, dp + 4096 + tid * 16);
  };

  // ---- prologue: x2v, X->LDS, S0..S2; all must land before loop entry ----
  f32x4 x2v[2];
  #pragma unroll
  for (int r = 0; r < 2; ++r)
    x2v[r] = *(const f32x4*)&x2g[b0 + wr * 32 + r * 16 + quad * 4];
  SB0();
  #pragma unroll
  for (int i = 0; i < 8; ++i)
    stage16(xsrc + i * 4096 + tid * 16, smem + i * 4096 + tid * 16);
  SB0();
  stage_grp(0, 0); SB0();
  stage_grp(0, 1); SB0();
  stage_grp(0, 2);
  WAITLG(0);                       // bufs 0,1,2 all readable without further sync
  __builtin_amdgcn_s_barrier();
  SB0();

  // fragment register double-buffers (R5-identical sizes)
  long long aF[2][2][2];     // [parity][k2][r]
  long long bF[2][2][4];     // [parity][k2][c]
  bf16x8 b2[2][4];           // gemm2 B, issued 2 slots ahead
  bf16x8 a2h[4][2];          // Ks slabs for this mt (hoisted per-mt)

  // ---- frag reads for slot 0 -> parity 0 ----
  #pragma unroll
  for (int k2 = 0; k2 < 2; ++k2) {
    #pragma unroll
    for (int r = 0; r < 2; ++r)
      aF[0][k2][r] = *(const long long*)(smem + ((k2 * 4 + quad) * 64 + wr * 32 + r * 16 + l16) * 8);
    #pragma unroll
    for (int c = 0; c < 4; ++c)
      bF[0][k2][c] = *(const long long*)(smem + 32768 +
                       ((k2 * 4 + quad) * 128 + wc * 64 + c * 16 + l16) * 8);
  }
  LGKM(0);
  __builtin_amdgcn_s_barrier();   // all waves' buf-0 reads done before slot-0 stage(g+4)->buf0
  SB0();

  const f32x4 zf = {0.f, 0.f, 0.f, 0.f};
  f32x4 acc_xs[2][4];
  f32x4 acc_out[2][4];
  #pragma unroll
  for (int r = 0; r < 2; ++r)
    #pragma unroll
    for (int c = 0; c < 4; ++c) { acc_xs[r][c] = zf; acc_out[r][c] = zf; }

  #pragma unroll 1
  for (int mt = 0; mt < 8; ++mt) {
    const int mtg = half * 8 + mt;

    // ---- mt-top: a2 hoist (after epilogue barrier => Ks(mt-1) visible) ----
    if (mt > 0) {
      #pragma unroll
      for (int ks = 0; ks < 4; ++ks) {
        const int kg = ks * 4 + quad;
        #pragma unroll
        for (int r = 0; r < 2; ++r)
          a2h[ks][r] = *(const bf16x8*)(smem + 65536 + (kg * 64 + wr * 32 + r * 16 + l16) * 16);
      }
      LGKM(0);
    }
    float s2v[4];

    #pragma unroll
    for (int grp = 0; grp < 8; ++grp) {
      const int p  = grp & 1;
      const int pn = p ^ 1;
      const int gN = grp + 1;                 // next slot
      const bool doRd = !(mt == 7 && grp == 7);

      // ---- even slot top: s2v / both stages (lead 3,4) / b2(g+2) ----
      if ((grp & 1) == 0) {
        if (grp == 0) {
          #pragma unroll
          for (int c = 0; c < 4; ++c)
            s2v[c] = s2g[mtg * 128 + wc * 64 + c * 16 + l16];
          SB0();
        }
        if (grp == 0)      { stage_grp(mt, 3); stage_grp(mt, 4); }
        else if (grp == 2) { stage_grp(mt, 5); stage_grp(mt, 6); }
        else if (grp == 4) { stage_grp(mt, 7); if (mt < 7) stage_grp(mt + 1, 0); }
        else               { if (mt < 7) { stage_grp(mt + 1, 1); stage_grp(mt + 1, 2); } }
        SB0();
        if ((grp < 6 && mt >= 1) || (grp == 6 && mt <= 6)) {
          const int um = mt + (grp == 6);
          const int ks = ((grp >> 1) + 1) & 3;
          const size_t sb = (size_t)((half * 8 + um - 1) * 16 + ks * 4 + quad);
          #pragma unroll
          for (int c = 0; c < 4; ++c)
            b2[((grp >> 1) + 1) & 1][c] = ldg_b128(hw_ws + (sb * 128 + wc * 64 + c * 16 + l16) * 8);
        }
        SB0();
      }

      // ---- MFMA chunk 1: k2=0 (8 fp8) | reads: 4 aF + 2 bF for slot gN ----
      __builtin_amdgcn_s_setprio(1);
      #pragma unroll
      for (int r = 0; r < 2; ++r)
        #pragma unroll
        for (int c = 0; c < 4; ++c)
          acc_xs[r][c] = __builtin_amdgcn_mfma_f32_16x16x32_fp8_fp8(
              aF[p][0][r], bF[p][0][c], acc_xs[r][c], 0, 0, 0);
      __builtin_amdgcn_s_setprio(0);
      SB0();
      if (doRd) {
        #pragma unroll
        for (int k2 = 0; k2 < 2; ++k2)
          #pragma unroll
          for (int r = 0; r < 2; ++r)
            aF[pn][k2][r] = *(const long long*)(smem +
                ((((gN & 7) * 2 + k2) * 4 + quad) * 64 + wr * 32 + r * 16 + l16) * 8);
        #pragma unroll
        for (int c = 0; c < 2; ++c)
          bF[pn][0][c] = *(const long long*)(smem + 32768 + (gN & 3) * 8192 +
              ((0 * 4 + quad) * 128 + wc * 64 + c * 16 + l16) * 8);
      }
      SB0();

      // ---- MFMA chunk 2: k2=1 (8 fp8) | reads: 6 bF for slot gN ----
      __builtin_amdgcn_s_setprio(1);
      #pragma unroll
      for (int r = 0; r < 2; ++r)
        #pragma unroll
        for (int c = 0; c < 4; ++c)
          acc_xs[r][c] = __builtin_amdgcn_mfma_f32_16x16x32_fp8_fp8(
              aF[p][1][r], bF[p][1][c], acc_xs[r][c], 0, 0, 0);
      __builtin_amdgcn_s_setprio(0);
      SB0();
      if (doRd) {
        #pragma unroll
        for (int c = 2; c < 4; ++c)
          bF[pn][0][c] = *(const long long*)(smem + 32768 + (gN & 3) * 8192 +
              ((0 * 4 + quad) * 128 + wc * 64 + c * 16 + l16) * 8);
        #pragma unroll
        for (int c = 0; c < 4; ++c)
          bF[pn][1][c] = *(const long long*)(smem + 32768 + (gN & 3) * 8192 +
              ((1 * 4 + quad) * 128 + wc * 64 + c * 16 + l16) * 8);
      }
      SB0();

      if ((grp & 1) == 0) {
        // ---- gemm2 (mt>0): regs only; then mid-interval LGKM (no barrier) ----
        if (mt > 0) {
          __builtin_amdgcn_s_setprio(1);
          #pragma unroll
          for (int r = 0; r < 2; ++r)
            #pragma unroll
            for (int c = 0; c < 4; ++c)
              acc_out[r][c] = __builtin_amdgcn_mfma_f32_16x16x32_bf16(
                  a2h[grp >> 1][r], b2[(grp >> 1) & 1][c], acc_out[r][c], 0, 0, 0);
          __builtin_amdgcn_s_setprio(0);
        }
        LGKM(0);                   // frag reads for the odd slot landed
      } else {
        // ---- interval end: drain all (stages ~2 slots old), publish ----
        WAITLG(0);
        __builtin_amdgcn_s_barrier();
        SB0();
      }
    }

    // ---- epilogue: t = acc + x2g + s2g ; k = min(exp2(-t),1) -> bf16 Ks ----
    {
      #pragma unroll
      for (int r = 0; r < 2; ++r)
        #pragma unroll
        for (int c = 0; c < 4; ++c) {
          const int cl = wc * 64 + c * 16 + l16;     // m-col 0..127
          char* kbase = smem + 65536 + (cl >> 3) * 1024 + (cl & 7) * 2;
          #pragma unroll
          for (int i = 0; i < 4; ++i) {
            const int row = wr * 32 + r * 16 + quad * 4 + i;
            const float t = acc_xs[r][c][i] + x2v[r][i] + s2v[c];
            float kv = __builtin_amdgcn_exp2f(-t);
            kv = fminf(kv, 1.0f);
            *(u16*)(kbase + row * 16) = (u16)(__float_as_uint(kv) >> 16);
            acc_xs[r][c][i] = 0.0f;
          }
        }
    }
    // Ks writes ordered before next mt's a2 hoist
    LGKM(0);
    __builtin_amdgcn_s_barrier();
    SB0();
  }

  // ---- drained GEMM2 for the last mtile (Ks(7)) ----
  #pragma unroll
  for (int ks = 0; ks < 4; ++ks) {
    const int kg = ks * 4 + quad;
    const size_t sb = (size_t)((half * 8 + 7) * 16 + kg);
    bf16x8 bb[4], aa[2];
    #pragma unroll
    for (int c = 0; c < 4; ++c)
      bb[c] = *(const bf16x8*)(hw_ws + (sb * 128 + wc * 64 + c * 16 + l16) * 8);
    #pragma unroll
    for (int r = 0; r < 2; ++r)
      aa[r] = *(const bf16x8*)(smem + 65536 + (kg * 64 + wr * 32 + r * 16 + l16) * 16);
    #pragma unroll
    for (int r = 0; r < 2; ++r)
      #pragma unroll
      for (int c = 0; c < 4; ++c)
        acc_out[r][c] = __builtin_amdgcn_mfma_f32_16x16x32_bf16(aa[r], bb[c], acc_out[r][c], 0, 0, 0);
  }

  // ---- final: atomic-accumulate scale*acc (+ bias/shift once, by half==0 blocks) ----
  float addv[4];
  #pragma unroll
  for (int c = 0; c < 4; ++c) {
    const int col = wc * 64 + c * 16 + l16;
    addv[c] = (half == 0) ? (vscale * head_b[col] + vshift) : 0.0f;
  }
  #pragma unroll
  for (int r = 0; r < 2; ++r)
    #pragma unroll
    for (int c = 0; c < 4; ++c) {
      const int col = wc * 64 + c * 16 + l16;
      #pragma unroll
      for (int i = 0; i < 4; ++i) {
        const int row = b0 + wr * 32 + r * 16 + quad * 4 + i;
        atomicAdd(&out[(size_t)row * NOUT + col], vscale * acc_out[r][c][i] + addv[c]);
      }
    }
}

// ---------- launch ----------
extern "C" void kernel_launch(void* const* d_in, const int* in_sizes, int n_in,
                              void* d_out, int out_size, void* d_ws, size_t ws_size,
                              hipStream_t stream) {
  const float* x       = (const float*)d_in[0];
  const float* support = (const float*)d_in[1];
  const float* gamma   = (const float*)d_in[2];
  const float* head_w  = (const float*)d_in[3];
  const float* head_b  = (const float*)d_in[4];
  const float* scale   = (const float*)d_in[5];
  const float* shift   = (const float*)d_in[6];
  float* out = (float*)d_out;

  char* w = (char*)d_ws;
  u8*    x_ws  = (u8*)(w);                        //  8,388,608 B
  u8*    s_ws  = (u8*)(w + 8388608);              //  2,097,152 B
  u16*   hw_ws = (u16*)(w + 10485760);            //  1,048,576 B
  float* x2g   = (float*)(w + 11534336);          //     65,536 B
  float* s2g   = (float*)(w + 11599872);          //     16,384 B

  static bool lds_init = false;
  if (!lds_init) {
    hipFuncSetAttribute(reinterpret_cast<const void*>(rbf_fused),
                        hipFuncAttributeMaxDynamicSharedMemorySize, 81920);
    lds_init = true;
  }

  prep_all<<<736, 256, 0, stream>>>(x, support, head_w, gamma,
                                    x_ws, s_ws, hw_ws, x2g, s2g, out);
  rbf_fused<<<1024, 256, 81920, stream>>>(x_ws, s_ws, hw_ws, x2g, s2g,
                                          head_b, scale, shift, out);
}